// Round 2
// baseline (204.350 us; speedup 1.0000x reference)
//
#include <hip/hip_runtime.h>

// LBP for semantic dependency parsing, reduced to label-difference form.
//
// Derivation (index-traced through the reference's transposes, spot-checked
// numerically against softplus form):
//   D[b,i,j,k] := (m[1]-m[0]) at reference position (l, x=j, y=i, z=k, b);
//   the score feeding it is s_*[b,i,j,k] (layouts coincide).
//   r = dQ[b,i,j] - D_old[b,i,j,k];  D_new = softplus(r+s) - softplus(r)
//     (log_softmax and the z-normalization cancel in the difference)
//   dQ_next[b,i,j] = s_edge[b,i,j]
//       + mask[b,i,j] * sum_c D_sum[b,c,j,i] * mask[b,c,j]*(c!=j)*(c!=i)
//   output[b,i,j] = sigmoid(dQ_final[b,i,j])
// log2 domain (Q' = log2e*Q, D' = log2e*D):
//   E = 2^(log2e*s) - 1;  p = 2^(-r');  D' = log2(1+p+E) - log2(1+p)
// Pass t recomputes D_1..D_t from the tiny Q' history, so bulk traffic is
// the three score tensors read once per pass.

#define TS 128

constexpr float LOG2E = 1.4426950408889634f;

__device__ __forceinline__ float fexp2(float x) { return exp2f(x); }     // v_exp_f32
__device__ __forceinline__ float flog2(float x) { return __log2f(x); }   // v_log_f32

// ---- mask format probe: 1 = byte mask, 2 = float32, 0 = int32 ----
__global__ void mask_detect(const unsigned char* __restrict__ m, int n, int* flag) {
    __shared__ int s1, s23;
    if (threadIdx.x == 0) { s1 = 0; s23 = 0; }
    __syncthreads();
    int v1 = 0, v23 = 0;
    for (int i = threadIdx.x; i < n; i += blockDim.x) {   // first n bytes: in-bounds for all layouts
        unsigned char b = m[i];
        int r = i & 3;
        if (r == 1) v1 |= b;
        if (r >= 2) v23 |= b;
    }
    if (v1)  atomicOr(&s1, 1);
    if (v23) atomicOr(&s23, 1);
    __syncthreads();
    if (threadIdx.x == 0) *flag = s1 ? 1 : (s23 ? 2 : 0);
}

__global__ void mask_normalize(const void* __restrict__ m, const int* __restrict__ flag,
                               unsigned char* __restrict__ nm, int n) {
    int i = blockIdx.x * blockDim.x + threadIdx.x;
    if (i >= n) return;
    const int f = *flag;
    unsigned char v;
    if (f == 1)      v = ((const unsigned char*)m)[i] != 0;
    else if (f == 2) v = ((const float*)m)[i] != 0.0f;
    else             v = ((const int*)m)[i] != 0;
    nm[i] = v;
}

// ---- main pass: one block per (b, j) ----
template <int PASS>
__global__ __launch_bounds__(256, 4)
void lbp_pass(const float* __restrict__ s_edge,
              const float* __restrict__ s_sib,
              const float* __restrict__ s_cop,
              const float* __restrict__ s_grd,
              const unsigned char* __restrict__ nmask,
              const float* __restrict__ Q1T,   // scaled dQ_1', transposed [b, j, i]
              const float* __restrict__ Q2T,   // scaled dQ_2', transposed [b, j, i]
              float* __restrict__ outp)        // pass1/2: QT [b,j,i]; pass3: out [b,i,j]
{
    __shared__ float qs0[TS];           // log2e * s_edge[b, i, j]  (dQ_0')
    __shared__ float qs1[TS];
    __shared__ float qs2[TS];
    __shared__ float p1r[TS];           // 2^(-Q0')
    __shared__ float lp1r[TS];          // log2(1 + p1)
    __shared__ float red[256];
    __shared__ unsigned char mrow[TS];  // mask[b, i, j]

    const int bj = blockIdx.x;
    const int b  = bj >> 7;
    const int j  = bj & (TS - 1);
    const int t  = threadIdx.x;
    const int k  = t & (TS - 1);
    const int h  = t >> 7;

    if (t < TS) {
        const int i = t;
        const float q0 = LOG2E * s_edge[(b * TS + i) * TS + j];
        qs0[i]  = q0;
        mrow[i] = nmask[(b * TS + i) * TS + j];
        const float p1 = fexp2(-q0);
        p1r[i]  = p1;
        lp1r[i] = flog2(1.0f + p1);
        if constexpr (PASS >= 2) qs1[i] = Q1T[(b * TS + j) * TS + i];
        if constexpr (PASS >= 3) qs2[i] = Q2T[(b * TS + j) * TS + i];
    }
    __syncthreads();

    const size_t base = ((size_t)b * TS * TS * TS) + (size_t)j * TS + k;

    auto row_term = [&](int i, float ss, float sc, float sg) -> float {
        if (!(mrow[i] != 0 && i != j)) return 0.0f;
        const float Es = fexp2(LOG2E * ss) - 1.0f;
        const float Ec = fexp2(LOG2E * sc) - 1.0f;
        const float Eg = fexp2(LOG2E * sg) - 1.0f;
        const float p1 = p1r[i], l1 = lp1r[i];
        float Ds = flog2(1.0f + p1 + Es) - l1;
        float Dc = flog2(1.0f + p1 + Ec) - l1;
        float Dg = flog2(1.0f + p1 + Eg) - l1;
        if constexpr (PASS >= 2) {
            const float q1 = qs1[i];
            const float ps = fexp2(fminf(Ds - q1, 126.0f));
            const float pc = fexp2(fminf(Dc - q1, 126.0f));
            const float pg = fexp2(fminf(Dg - q1, 126.0f));
            Ds = flog2(1.0f + ps + Es) - flog2(1.0f + ps);
            Dc = flog2(1.0f + pc + Ec) - flog2(1.0f + pc);
            Dg = flog2(1.0f + pg + Eg) - flog2(1.0f + pg);
        }
        if constexpr (PASS >= 3) {
            const float q2 = qs2[i];
            const float ps = fexp2(fminf(Ds - q2, 126.0f));
            const float pc = fexp2(fminf(Dc - q2, 126.0f));
            const float pg = fexp2(fminf(Dg - q2, 126.0f));
            Ds = flog2(1.0f + ps + Es) - flog2(1.0f + ps);
            Dc = flog2(1.0f + pc + Ec) - flog2(1.0f + pc);
            Dg = flog2(1.0f + pg + Eg) - flog2(1.0f + pg);
        }
        const float dt = Ds + Dc + Dg;
        return (k == i) ? 0.0f : dt;
    };

    float acc = 0.0f;
    for (int i0 = 0; i0 < TS; i0 += 4) {
        const int ia = i0 + h;
        const int ib = ia + 2;
        const size_t offa = base + (size_t)ia * (TS * TS);
        const size_t offb = base + (size_t)ib * (TS * TS);
        const float ssa = s_sib[offa], sca = s_cop[offa], sga = s_grd[offa];
        const float ssb = s_sib[offb], scb = s_cop[offb], sgb = s_grd[offb];
        acc += row_term(ia, ssa, sca, sga);
        acc += row_term(ib, ssb, scb, sgb);
    }

    red[t] = acc;
    __syncthreads();

    if (t < TS) {
        const float tot = red[t] + red[t + TS];
        const float q = qs0[t] + ((mrow[t] != 0) ? tot : 0.0f);
        if constexpr (PASS < 3) {
            outp[(b * TS + j) * TS + t] = q;                       // transposed, coalesced
        } else {
            outp[(b * TS + t) * TS + j] = 1.0f / (1.0f + fexp2(-q));
        }
    }
}

extern "C" void kernel_launch(void* const* d_in, const int* in_sizes, int n_in,
                              void* d_out, int out_size, void* d_ws, size_t ws_size,
                              hipStream_t stream) {
    const float* s_edge = (const float*)d_in[0];
    const float* s_sib  = (const float*)d_in[1];
    const float* s_cop  = (const float*)d_in[2];
    const float* s_grd  = (const float*)d_in[3];
    const void*  mask   = d_in[4];
    float* out = (float*)d_out;

    const int Bn = in_sizes[0] / (TS * TS);     // batch
    const int nMask = in_sizes[4];              // B*S*S elements

    float* Q1T = (float*)d_ws;
    float* Q2T = Q1T + (size_t)Bn * TS * TS;
    unsigned char* nmask = (unsigned char*)(Q2T + (size_t)Bn * TS * TS);
    int* flag = (int*)(nmask + (size_t)nMask);

    mask_detect<<<1, 1024, 0, stream>>>((const unsigned char*)mask, nMask, flag);
    mask_normalize<<<(nMask + 255) / 256, 256, 0, stream>>>(mask, flag, nmask, nMask);

    dim3 grid(Bn * TS), block(256);
    lbp_pass<1><<<grid, block, 0, stream>>>(s_edge, s_sib, s_cop, s_grd, nmask,
                                            nullptr, nullptr, Q1T);
    lbp_pass<2><<<grid, block, 0, stream>>>(s_edge, s_sib, s_cop, s_grd, nmask,
                                            Q1T, nullptr, Q2T);
    lbp_pass<3><<<grid, block, 0, stream>>>(s_edge, s_sib, s_cop, s_grd, nmask,
                                            Q1T, Q2T, out);
}

// Round 3
// 202.705 us; speedup vs baseline: 1.0081x; 1.0081x over previous
//
#include <hip/hip_runtime.h>

// LBP for semantic dependency parsing, reduced to label-difference form.
//
//   D[b,i,j,k] := (m[1]-m[0]) at reference position (l, x=j, y=i, z=k, b);
//   r = dQ[b,i,j] - D_old[b,i,j,k];  D_new = softplus(r+s) - softplus(r)
//   dQ_next[b,i,j] = s_edge[b,i,j]
//       + mask[b,i,j] * sum_c D_sum[b,c,j,i] * mask[b,c,j]*(c!=j)*(c!=i)
//   output[b,i,j] = sigmoid(dQ_final[b,i,j])
// log2 domain: E = 2^(log2e*s)-1;  p = 2^(-r');  D' = log2(1+p+E) - log2(1+p)
// Pass t recomputes D_1..D_t from the tiny Q' history; bulk traffic is the
// three score tensors read once per pass, as float4 (dwordx4) loads.

#define TS 128

constexpr float LOG2E = 1.4426950408889634f;

// ---- mask format probe: 1 = byte mask, 2 = float32, 0 = int32 ----
__global__ void mask_detect(const unsigned char* __restrict__ m, int n, int* flag) {
    __shared__ int s1, s23;
    if (threadIdx.x == 0) { s1 = 0; s23 = 0; }
    __syncthreads();
    int v1 = 0, v23 = 0;
    for (int i = threadIdx.x; i < n; i += blockDim.x) {
        unsigned char b = m[i];
        int r = i & 3;
        if (r == 1) v1 |= b;
        if (r >= 2) v23 |= b;
    }
    if (v1)  atomicOr(&s1, 1);
    if (v23) atomicOr(&s23, 1);
    __syncthreads();
    if (threadIdx.x == 0) *flag = s1 ? 1 : (s23 ? 2 : 0);
}

__global__ void mask_normalize(const void* __restrict__ m, const int* __restrict__ flag,
                               unsigned char* __restrict__ nm, int n) {
    int i = blockIdx.x * blockDim.x + threadIdx.x;
    if (i >= n) return;
    const int f = *flag;
    unsigned char v;
    if (f == 1)      v = ((const unsigned char*)m)[i] != 0;
    else if (f == 2) v = ((const float*)m)[i] != 0.0f;
    else             v = ((const int*)m)[i] != 0;
    nm[i] = v;
}

// ---- main pass: one block per (b, j); thread = (k-quad, row-group) ----
template <int PASS>
__global__ __launch_bounds__(256, 4)
void lbp_pass(const float* __restrict__ s_edge,
              const float4* __restrict__ s_sib,
              const float4* __restrict__ s_cop,
              const float4* __restrict__ s_grd,
              const unsigned char* __restrict__ nmask,
              const float* __restrict__ Q1T,   // scaled dQ_1', transposed [b, j, i]
              const float* __restrict__ Q2T,   // scaled dQ_2', transposed [b, j, i]
              float* __restrict__ outp)        // pass1/2: QT [b,j,i]; pass3: out [b,i,j]
{
    __shared__ float qs0[TS];           // log2e * s_edge[b, i, j]
    __shared__ float qs1[TS];
    __shared__ float qs2[TS];
    __shared__ float p1r[TS];           // 2^(-Q0')
    __shared__ float lp1r[TS];          // log2(1 + p1)
    __shared__ float4 red4[8 * 32];     // [row-group][k-quad]
    __shared__ unsigned char mrow[TS];

    const int bj = blockIdx.x;
    const int b  = bj >> 7;
    const int j  = bj & (TS - 1);
    const int t  = threadIdx.x;
    const int kq = t & 31;              // k-quad: k = 4*kq .. 4*kq+3
    const int rg = t >> 5;              // row group 0..7 (16 rows each)

    if (t < TS) {
        const int i = t;
        const float q0 = LOG2E * s_edge[(b * TS + i) * TS + j];
        qs0[i]  = q0;
        mrow[i] = nmask[(b * TS + i) * TS + j];
        const float p1 = exp2f(-q0);
        p1r[i]  = p1;
        lp1r[i] = __log2f(1.0f + p1);
        if constexpr (PASS >= 2) qs1[i] = Q1T[(b * TS + j) * TS + i]; else qs1[i] = 0.0f;
        if constexpr (PASS >= 3) qs2[i] = Q2T[(b * TS + j) * TS + i]; else qs2[i] = 0.0f;
    }
    __syncthreads();

    // float4 index of (b, i, j, k=4*kq):  element ((b*TS+i)*TS + j)*TS + 4*kq
    const size_t base4 = ((size_t)b * TS * TS * TS + (size_t)j * TS) / 4 + kq;
    const int rowStride4 = TS * TS / 4;             // 4096 float4 per row step in i

    float acc0 = 0.0f, acc1 = 0.0f, acc2 = 0.0f, acc3 = 0.0f;
    const int i_beg = rg * 16;
    const int k0 = kq * 4;

    #pragma unroll 2
    for (int ii = 0; ii < 16; ++ii) {
        const int i = i_beg + ii;
        const size_t off = base4 + (size_t)i * rowStride4;
        const float4 vs = s_sib[off];
        const float4 vc = s_cop[off];
        const float4 vg = s_grd[off];
        if (!(mrow[i] != 0 && i != j)) continue;

        const float p1 = p1r[i], l1 = lp1r[i];
        const float q1 = qs1[i], q2 = qs2[i];
        const float sarr[4] = {vs.x, vs.y, vs.z, vs.w};
        const float carr[4] = {vc.x, vc.y, vc.z, vc.w};
        const float garr[4] = {vg.x, vg.y, vg.z, vg.w};
        float res[4];
        #pragma unroll
        for (int q = 0; q < 4; ++q) {
            const float Es = exp2f(LOG2E * sarr[q]) - 1.0f;
            const float Ec = exp2f(LOG2E * carr[q]) - 1.0f;
            const float Eg = exp2f(LOG2E * garr[q]) - 1.0f;
            float Ds = __log2f(1.0f + p1 + Es) - l1;
            float Dc = __log2f(1.0f + p1 + Ec) - l1;
            float Dg = __log2f(1.0f + p1 + Eg) - l1;
            if constexpr (PASS >= 2) {
                const float ps = exp2f(fminf(Ds - q1, 126.0f));
                const float pc = exp2f(fminf(Dc - q1, 126.0f));
                const float pg = exp2f(fminf(Dg - q1, 126.0f));
                Ds = __log2f(1.0f + ps + Es) - __log2f(1.0f + ps);
                Dc = __log2f(1.0f + pc + Ec) - __log2f(1.0f + pc);
                Dg = __log2f(1.0f + pg + Eg) - __log2f(1.0f + pg);
            }
            if constexpr (PASS >= 3) {
                const float ps = exp2f(fminf(Ds - q2, 126.0f));
                const float pc = exp2f(fminf(Dc - q2, 126.0f));
                const float pg = exp2f(fminf(Dg - q2, 126.0f));
                Ds = __log2f(1.0f + ps + Es) - __log2f(1.0f + ps);
                Dc = __log2f(1.0f + pc + Ec) - __log2f(1.0f + pc);
                Dg = __log2f(1.0f + pg + Eg) - __log2f(1.0f + pg);
            }
            res[q] = Ds + Dc + Dg;
        }
        acc0 += (k0 + 0 == i) ? 0.0f : res[0];
        acc1 += (k0 + 1 == i) ? 0.0f : res[1];
        acc2 += (k0 + 2 == i) ? 0.0f : res[2];
        acc3 += (k0 + 3 == i) ? 0.0f : res[3];
    }

    red4[rg * 32 + kq] = make_float4(acc0, acc1, acc2, acc3);
    __syncthreads();

    if (t < TS) {
        const float* red = (const float*)red4;
        float tot = 0.0f;
        #pragma unroll
        for (int g = 0; g < 8; ++g) tot += red[g * TS + t];
        const float q = qs0[t] + ((mrow[t] != 0) ? tot : 0.0f);
        if constexpr (PASS < 3) {
            outp[(b * TS + j) * TS + t] = q;                  // transposed, coalesced
        } else {
            outp[(b * TS + t) * TS + j] = 1.0f / (1.0f + exp2f(-q));
        }
    }
}

extern "C" void kernel_launch(void* const* d_in, const int* in_sizes, int n_in,
                              void* d_out, int out_size, void* d_ws, size_t ws_size,
                              hipStream_t stream) {
    const float* s_edge = (const float*)d_in[0];
    const float4* s_sib = (const float4*)d_in[1];
    const float4* s_cop = (const float4*)d_in[2];
    const float4* s_grd = (const float4*)d_in[3];
    const void*  mask   = d_in[4];
    float* out = (float*)d_out;

    const int Bn = in_sizes[0] / (TS * TS);     // batch
    const int nMask = in_sizes[4];              // B*S*S elements

    float* Q1T = (float*)d_ws;
    float* Q2T = Q1T + (size_t)Bn * TS * TS;
    unsigned char* nmask = (unsigned char*)(Q2T + (size_t)Bn * TS * TS);
    int* flag = (int*)(nmask + (size_t)nMask);

    mask_detect<<<1, 1024, 0, stream>>>((const unsigned char*)mask, nMask, flag);
    mask_normalize<<<(nMask + 255) / 256, 256, 0, stream>>>(mask, flag, nmask, nMask);

    dim3 grid(Bn * TS), block(256);
    lbp_pass<1><<<grid, block, 0, stream>>>(s_edge, s_sib, s_cop, s_grd, nmask,
                                            nullptr, nullptr, Q1T);
    lbp_pass<2><<<grid, block, 0, stream>>>(s_edge, s_sib, s_cop, s_grd, nmask,
                                            Q1T, nullptr, Q2T);
    lbp_pass<3><<<grid, block, 0, stream>>>(s_edge, s_sib, s_cop, s_grd, nmask,
                                            Q1T, Q2T, out);
}

// Round 4
// 111.332 us; speedup vs baseline: 1.8355x; 1.8207x over previous
//
#include <hip/hip_runtime.h>

// LBP for semantic dependency parsing — label-difference form, all 3
// iterations FUSED into one kernel.
//
//   E[b,i,j,k]  = 2^(log2e*s[b,i,j,k]) - 1          (only use of the scores)
//   D_0 = 0;  D_t = log2(1+p+E) - log2(1+p),  p = 2^(D_{t-1} - q_{t-1}[i])
//   q_t[k] = q0[k] + mask[k] * sum_i D^sum_t[i,k] * mask[i]*(i!=j)*(i!=k)
//   out[b,k,j] = 1/(1+2^(-q_3[k]))
// The whole recursion for column j closes inside block (b,j): the block's own
// reduction produces the q-column it needs next pass. Scores are read from
// HBM exactly once, staged as E in registers; message state D lives in
// registers across passes.

#define TS 128
#define ROWS 8          // rows per thread (512 threads: 16 row-groups x 32 k-quads)

typedef float f4v __attribute__((ext_vector_type(4)));

constexpr float LOG2E = 1.4426950408889634f;

// ---- mask format probe: f[0]!=0 -> byte mask, f[1]!=0 -> float32, else int32
__global__ void flags_init(int* __restrict__ f) { f[0] = 0; f[1] = 0; }

__global__ void mask_detect(const unsigned char* __restrict__ m, int n, int* __restrict__ f) {
    int v1 = 0, v23 = 0;
    for (int i = blockIdx.x * blockDim.x + threadIdx.x; i < n; i += gridDim.x * blockDim.x) {
        const unsigned char b = m[i];           // first n bytes: in-bounds for all layouts
        const int r = i & 3;
        if (r == 1) v1 |= b;
        if (r >= 2) v23 |= b;
    }
    const int lane = threadIdx.x & 63;
    if (__any(v1)  && lane == 0) atomicOr(&f[0], 1);
    if (__any(v23) && lane == 0) atomicOr(&f[1], 1);
}

__global__ __launch_bounds__(512)
void lbp_fused(const float* __restrict__ s_edge,
               const f4v* __restrict__ sib4,
               const f4v* __restrict__ cop4,
               const f4v* __restrict__ grd4,
               const void* __restrict__ mask,
               const int* __restrict__ flags,
               float* __restrict__ outp)
{
    __shared__ float qs[TS], q0s[TS], p1s[TS], lp1s[TS];
    __shared__ f4v red4[16 * 32];
    __shared__ unsigned char mrow[TS];

    const int bj = blockIdx.x;
    const int b  = bj >> 7;
    const int j  = bj & (TS - 1);
    const int t  = threadIdx.x;
    const int kq = t & 31;          // k-quad: k = 4*kq..4*kq+3
    const int rq = t >> 5;          // row-group 0..15
    const int i0 = rq * ROWS;
    const int k0 = kq * 4;

    // ---- stage scores -> E registers (single HBM read of the bulk data) ----
    f4v Es[ROWS], Ec[ROWS], Eg[ROWS], Ds[ROWS], Dc[ROWS], Dg[ROWS];
    const size_t colBase4 = (size_t)b * (TS * TS * TS / 4) + (size_t)j * (TS / 4) + kq;
    #pragma unroll
    for (int r = 0; r < ROWS; ++r) {
        const size_t off = colBase4 + (size_t)(i0 + r) * (TS * TS / 4);
        const f4v vs = sib4[off];
        const f4v vc = cop4[off];
        const f4v vg = grd4[off];
        #pragma unroll
        for (int c = 0; c < 4; ++c) {
            Es[r][c] = exp2f(LOG2E * vs[c]) - 1.0f;
            Ec[r][c] = exp2f(LOG2E * vc[c]) - 1.0f;
            Eg[r][c] = exp2f(LOG2E * vg[c]) - 1.0f;
        }
    }

    if (t < TS) {
        const int i = t;
        const int idx = (b * TS + i) * TS + j;
        const float q0 = LOG2E * s_edge[idx];
        q0s[i] = q0;
        qs[i]  = q0;
        const int f1 = flags[0], f23 = flags[1];
        unsigned char mv;
        if (f1)       mv = ((const unsigned char*)mask)[idx] != 0;
        else if (f23) mv = ((const float*)mask)[idx] != 0.0f;
        else          mv = ((const int*)mask)[idx]   != 0;
        mrow[i] = mv;
        const float p1 = exp2f(-q0);
        p1s[i]  = p1;
        lp1s[i] = __log2f(1.0f + p1);
    }
    __syncthreads();

    // ---- pass 1 (D_old = 0: p = 2^-q0 shared per row) ----
    f4v acc;
    acc[0] = acc[1] = acc[2] = acc[3] = 0.0f;
    #pragma unroll
    for (int r = 0; r < ROWS; ++r) {
        const int i = i0 + r;
        if (mrow[i] && i != j) {
            const float p1 = p1s[i], l1 = lp1s[i];
            #pragma unroll
            for (int c = 0; c < 4; ++c) {
                const float ds = __log2f(1.0f + p1 + Es[r][c]) - l1;
                const float dc = __log2f(1.0f + p1 + Ec[r][c]) - l1;
                const float dg = __log2f(1.0f + p1 + Eg[r][c]) - l1;
                Ds[r][c] = ds; Dc[r][c] = dc; Dg[r][c] = dg;
                acc[c] += (i == k0 + c) ? 0.0f : (ds + dc + dg);
            }
        }
    }
    red4[rq * 32 + kq] = acc;
    __syncthreads();
    if (t < TS) {
        const float* red = (const float*)red4;
        float tot = 0.0f;
        #pragma unroll
        for (int g = 0; g < 16; ++g) tot += red[g * TS + t];
        qs[t] = q0s[t] + (mrow[t] ? tot : 0.0f);
    }
    __syncthreads();

    // ---- passes 2 and 3 (per-element D state in registers) ----
    for (int pass = 0; pass < 2; ++pass) {
        acc[0] = acc[1] = acc[2] = acc[3] = 0.0f;
        #pragma unroll
        for (int r = 0; r < ROWS; ++r) {
            const int i = i0 + r;
            if (mrow[i] && i != j) {
                const float q = qs[i];
                #pragma unroll
                for (int c = 0; c < 4; ++c) {
                    float p, a, dn, s;
                    p = exp2f(fminf(Ds[r][c] - q, 126.0f));
                    a = 1.0f + p;
                    dn = __log2f(a + Es[r][c]) - __log2f(a);
                    Ds[r][c] = dn; s = dn;
                    p = exp2f(fminf(Dc[r][c] - q, 126.0f));
                    a = 1.0f + p;
                    dn = __log2f(a + Ec[r][c]) - __log2f(a);
                    Dc[r][c] = dn; s += dn;
                    p = exp2f(fminf(Dg[r][c] - q, 126.0f));
                    a = 1.0f + p;
                    dn = __log2f(a + Eg[r][c]) - __log2f(a);
                    Dg[r][c] = dn; s += dn;
                    acc[c] += (i == k0 + c) ? 0.0f : s;
                }
            }
        }
        red4[rq * 32 + kq] = acc;
        __syncthreads();
        if (t < TS) {
            const float* red = (const float*)red4;
            float tot = 0.0f;
            #pragma unroll
            for (int g = 0; g < 16; ++g) tot += red[g * TS + t];
            qs[t] = q0s[t] + (mrow[t] ? tot : 0.0f);
        }
        __syncthreads();
    }

    if (t < TS)
        outp[(b * TS + t) * TS + j] = 1.0f / (1.0f + exp2f(-qs[t]));
}

extern "C" void kernel_launch(void* const* d_in, const int* in_sizes, int n_in,
                              void* d_out, int out_size, void* d_ws, size_t ws_size,
                              hipStream_t stream) {
    const float* s_edge = (const float*)d_in[0];
    const f4v*   sib4   = (const f4v*)d_in[1];
    const f4v*   cop4   = (const f4v*)d_in[2];
    const f4v*   grd4   = (const f4v*)d_in[3];
    const void*  mask   = d_in[4];
    float* out = (float*)d_out;

    const int Bn = in_sizes[0] / (TS * TS);   // batch
    const int nMask = in_sizes[4];            // B*S*S elements

    int* flags = (int*)d_ws;

    flags_init<<<1, 1, 0, stream>>>(flags);
    mask_detect<<<64, 256, 0, stream>>>((const unsigned char*)mask, nMask, flags);
    lbp_fused<<<Bn * TS, 512, 0, stream>>>(s_edge, sib4, cop4, grd4, mask, flags, out);
}